// Round 13
// baseline (153.456 us; speedup 1.0000x reference)
//
#include <hip/hip_runtime.h>
#include <hip/hip_bf16.h>

typedef _Float16 f16x8 __attribute__((ext_vector_type(8)));
typedef _Float16 f16x4 __attribute__((ext_vector_type(4)));
typedef _Float16 f16x2 __attribute__((ext_vector_type(2)));
typedef __fp16 h16x2 __attribute__((ext_vector_type(2)));
typedef float f32x4 __attribute__((ext_vector_type(4)));
typedef unsigned int u32;

#define MFMA16(a, b, c) __builtin_amdgcn_mfma_f32_16x16x32_f16(a, b, c, 0, 0, 0)

// q pre-scale: sqrt(64) * log2(e)  (exp2-domain softmax)
#define QSCALE 11.54156032f
// defer-max threshold (log2 domain; ~8 nats). P bounded by 2^11.55 < f16 max.
#define THR_DEFER 11.54156032f

__device__ __forceinline__ void gld16(const void* g, void* l) {
  using gp_t = const __attribute__((address_space(1))) u32*;
  using lp_t = __attribute__((address_space(3))) u32*;
  __builtin_amdgcn_global_load_lds((gp_t)g, (lp_t)l, 16, 0, 0);
}

__device__ __forceinline__ float fmax3(float a, float b, float c) {
  float d;
  asm("v_max3_f32 %0, %1, %2, %3" : "=v"(d) : "v"(a), "v"(b), "v"(c));
  return d;
}

__device__ __forceinline__ f16x2 pk2(float lo, float hi) {
  h16x2 r = __builtin_amdgcn_cvt_pkrtz(lo, hi);
  return __builtin_bit_cast(f16x2, r);
}

// ---------------- fused prep: x f32->f16 + both weight transposes ----------
__global__ __launch_bounds__(256) void prep_kernel(
    const float* __restrict__ x, _Float16* __restrict__ xb,
    const float* __restrict__ wqkv, _Float16* __restrict__ wqkvt,
    const float* __restrict__ wout, _Float16* __restrict__ woutt) {
  __shared__ float t[32][33];
  const int bid = blockIdx.x, tid = threadIdx.x;
  if (bid < 4096) {
    const int i = (bid * 256 + tid) * 4;
    float4 v = *(const float4*)(x + i);
    f16x4 h = {(_Float16)v.x, (_Float16)v.y, (_Float16)v.z, (_Float16)v.w};
    *(f16x4*)(xb + i) = h;
    return;
  }
  const float* in;
  _Float16* out;
  int C, bx, by;
  if (bid < 7168) {
    const int b2 = bid - 4096;
    in = wqkv; out = wqkvt; C = 3072;
    bx = (b2 % 96) * 32; by = (b2 / 96) * 32;
  } else {
    const int b2 = bid - 7168;
    in = wout; out = woutt; C = 1024;
    bx = (b2 & 31) * 32; by = (b2 >> 5) * 32;
  }
  const int tx = tid & 31, ty = tid >> 5;
  for (int i = 0; i < 32; i += 8)
    t[ty + i][tx] = in[(size_t)(by + ty + i) * C + bx + tx];
  __syncthreads();
  for (int i = 0; i < 32; i += 8)
    out[(size_t)(bx + ty + i) * 1024 + by + tx] = (_Float16)t[tx][ty + i];
}

// ---------------- 128xBN tile GEMM, BK=64 (unchanged from R12) -------------
template <int MODE, int NTILE>
__global__ __launch_bounds__(256) void gemm128(
    const _Float16* __restrict__ A, const _Float16* __restrict__ Bt, int Kd,
    _Float16* __restrict__ qo, _Float16* __restrict__ ko, _Float16* __restrict__ vt,
    float* __restrict__ fo, int Nd) {
  constexpr int BN = NTILE * 32;
  constexpr int SHSZ = (MODE == 0) ? 16640 : (128 * 64 + BN * 64);
  __shared__ __align__(16) _Float16 SH[SHSZ];
  _Float16* As = SH;
  _Float16* Bs = SH + 128 * 64;
  const int tid = threadIdx.x;
  const int w = tid >> 6, l = tid & 63;
  const int wm = w >> 1, wn = w & 1;
  const int lr = l & 15, lg = l >> 4;
  const int nwg = gridDim.x;
  int lin = blockIdx.x;
  lin = (lin & 7) * (nwg >> 3) + (lin >> 3);
  const int m0 = (lin & 31) * 128, n0 = (lin >> 5) * BN;

  const int srow = tid >> 3;
  const int scol = ((tid & 7) ^ (srow & 7)) * 8;
  const int swzr = (lr & 7) << 3;

  f32x4 acc[4][NTILE];
  for (int i = 0; i < 4; ++i)
    for (int j = 0; j < NTILE; ++j) acc[i][j] = (f32x4){0.f, 0.f, 0.f, 0.f};

  const int NT = Kd >> 6;
  for (int kt = 0; kt < NT; ++kt) {
    const int k0 = kt * 64;
    for (int c = 0; c < 4; ++c) {
      const int row = c * 32 + srow;
      gld16(A + (size_t)(m0 + row) * Kd + k0 + scol, &As[(c * 32 + w * 8) * 64]);
    }
    for (int c = 0; c < NTILE; ++c) {
      const int row = c * 32 + srow;
      gld16(Bt + (size_t)(n0 + row) * Kd + k0 + scol, &Bs[(c * 32 + w * 8) * 64]);
    }
    __syncthreads();
    for (int kk = 0; kk < 2; ++kk) {
      f16x8 af[4], bf[NTILE];
      const int cofs = (kk * 32 + lg * 8) ^ swzr;
      for (int mt = 0; mt < 4; ++mt)
        af[mt] = *(const f16x8*)&As[(wm * 64 + mt * 16 + lr) * 64 + cofs];
      for (int nt = 0; nt < NTILE; ++nt)
        bf[nt] = *(const f16x8*)&Bs[(wn * (NTILE * 16) + nt * 16 + lr) * 64 + cofs];
      for (int mt = 0; mt < 4; ++mt)
        for (int nt = 0; nt < NTILE; ++nt)
          acc[mt][nt] = MFMA16(af[mt], bf[nt], acc[mt][nt]);
    }
    __syncthreads();
  }

  if (MODE == 0 && n0 >= 2048) {
    // V-section block: transpose via LDS, store V^T rows coalesced.
    for (int mt = 0; mt < 4; ++mt)
      for (int nt = 0; nt < NTILE; ++nt)
        for (int r = 0; r < 4; ++r) {
          const int row = wm * 64 + mt * 16 + lg * 4 + r;    // ns-rel
          const int col = wn * (NTILE * 16) + nt * 16 + lr;  // gn-rel
          SH[row * 130 + col] = (_Float16)acc[mt][nt][r];
        }
    __syncthreads();
    const int b = m0 >> 11;
    const int hbase = (n0 & 1023) >> 6;
    const int c = tid >> 1, half = tid & 1;
    const int h2 = c >> 6, d = c & 63;
    _Float16* dst = vt + ((size_t)((b * 16 + hbase + h2) * 64 + d)) * 2048 +
                    (m0 & 2047) + half * 64;
    for (int j = 0; j < 8; ++j) {
      f16x8 v;
      for (int e = 0; e < 8; ++e) v[e] = SH[(half * 64 + j * 8 + e) * 130 + c];
      *(f16x8*)(dst + j * 8) = v;
    }
    return;
  }

  for (int mt = 0; mt < 4; ++mt)
    for (int nt = 0; nt < NTILE; ++nt) {
      const int gmB = m0 + wm * 64 + mt * 16 + lg * 4;
      const int gn = n0 + wn * (NTILE * 16) + nt * 16 + lr;
      for (int r = 0; r < 4; ++r) {
        const int gm = gmB + r;
        const float v = acc[mt][nt][r];
        if (MODE == 0) {
          const int b = gm >> 11, ns = gm & 2047;
          const int sect = gn >> 10, rem = gn & 1023;
          const int h = rem >> 6, d = rem & 63;
          const size_t bh = (size_t)b * 16 + h;
          if (sect == 0)
            qo[(bh * 2048 + ns) * 64 + d] = (_Float16)(v * QSCALE);
          else
            ko[(bh * 2048 + ns) * 64 + d] = (_Float16)v;
        } else {
          fo[(size_t)gm * Nd + gn] = v;
        }
      }
    }
}

// ---------------- flash attention v10 ----------------
// VALU-issue cuts on the proven v9 structure:
//  (a) QK accumulator C-in = nmr4 = broadcast(-m): kills acc-zero movs AND
//      the 16 pre-exp subs. State invariant: sc = S - m. Init m=0 is safe:
//      tile 0's huge tm forces the rescale branch (ao/lsum still zero), and
//      sc is clamped by `sc -= pos` before any exp2 -> sc <= THR always.
//  (b) row-sum via MFMA(pf, ones, lsum4) on the idle matrix pipe: kills the
//      fdot2 chain AND the final cross-lane sum (lsum4 is already in C-layout
//      q = lg*4+r, matching the ao rows).
//  (c) rescale subs/updates live inside the rare defer branch only.
__global__ __launch_bounds__(256) void attn_kernel(
    const _Float16* __restrict__ Q, const _Float16* __restrict__ K,
    const _Float16* __restrict__ Vt, _Float16* __restrict__ AO) {
  __shared__ __align__(16) _Float16 Kls[64 * 64];      // [key][d], swizzled
  __shared__ __align__(16) _Float16 Vls[64 * 64];      // [d][key], swizzled
  __shared__ __align__(16) _Float16 Pls[4 * 16 * 64];  // per-wave [q][key], swizzled
  const int bid = blockIdx.x;
  const int xcd = bid & 7, slot = bid >> 3;  // HW: consecutive bid -> XCDs RR
  const int bh = xcd * 4 + (slot >> 5);      // 4 bh per XCD (KV fits per-XCD L2)
  const int qt = slot & 31;
  const int b = bh >> 4, h = bh & 15;
  const int tid = threadIdx.x, w = tid >> 6, l = tid & 63;
  const int lr = l & 15, lg = l >> 4;
  const int q0 = qt * 64;
  const int pswz = (lr & 7) << 3;

  f16x8 qf[2];
  {
    const _Float16* qp = Q + ((size_t)bh * 2048 + q0 + w * 16 + lr) * 64 + lg * 8;
    qf[0] = *(const f16x8*)qp;
    qf[1] = *(const f16x8*)(qp + 32);
  }
  const f16x8 ones8 = {(_Float16)1.f, (_Float16)1.f, (_Float16)1.f, (_Float16)1.f,
                       (_Float16)1.f, (_Float16)1.f, (_Float16)1.f, (_Float16)1.f};
  f32x4 nmr4 = {0.f, 0.f, 0.f, 0.f};   // broadcast(-m) for q = w*16+lr; m init 0
  f32x4 lsum4 = {0.f, 0.f, 0.f, 0.f};  // running row sums, q = lg*4+r (C-layout)
  f32x4 ao[4];
  for (int dt = 0; dt < 4; ++dt) ao[dt] = (f32x4){0.f, 0.f, 0.f, 0.f};

  const int srow = tid >> 2, cb = tid & 3;
  const _Float16* Kbase = K + ((size_t)bh * 2048 + srow) * 64 + cb * 8;
  const _Float16* Vbase = Vt + ((size_t)bh * 64 + srow) * 2048 + cb * 8;
  const int lofs0 = srow * 64 + ((cb ^ (srow & 7)) << 3);
  const int lofs1 = srow * 64 + (((cb + 4) ^ (srow & 7)) << 3);

  f16x8 kr0, kr1, vr0, vr1;
  kr0 = *(const f16x8*)(Kbase);
  kr1 = *(const f16x8*)(Kbase + 32);
  vr0 = *(const f16x8*)(Vbase);
  vr1 = *(const f16x8*)(Vbase + 32);
  *(f16x8*)&Kls[lofs0] = kr0;
  *(f16x8*)&Kls[lofs1] = kr1;
  *(f16x8*)&Vls[lofs0] = vr0;
  *(f16x8*)&Vls[lofs1] = vr1;
  __syncthreads();

  _Float16* pw = &Pls[w * (16 * 64)];
  const int NT = 2048 / 64;
  for (int t = 0; t < NT; ++t) {
    if (t + 1 < NT) {  // issue next tile's loads early
      const size_t g = (size_t)(t + 1) * 64;
      kr0 = *(const f16x8*)(Kbase + g * 64);
      kr1 = *(const f16x8*)(Kbase + g * 64 + 32);
      vr0 = *(const f16x8*)(Vbase + g);
      vr1 = *(const f16x8*)(Vbase + g + 32);
    }
    // ---- sc = S - m directly via C-in bias ----
    f32x4 sc[4];
    __builtin_amdgcn_s_setprio(1);
    for (int ct = 0; ct < 4; ++ct) {
      f16x8 kf0 = *(const f16x8*)&Kls[(ct * 16 + lr) * 64 + ((lg * 8) ^ pswz)];
      f16x8 kf1 = *(const f16x8*)&Kls[(ct * 16 + lr) * 64 + ((32 + lg * 8) ^ pswz)];
      sc[ct] = MFMA16(kf0, qf[0], nmr4);
      sc[ct] = MFMA16(kf1, qf[1], sc[ct]);
    }
    __builtin_amdgcn_s_setprio(0);
    // ---- row max of (S - m) over 64 keys ----
    float tm = fmax3(sc[0][0], sc[0][1], sc[0][2]);
    float tm2 = fmax3(sc[0][3], sc[1][0], sc[1][1]);
    float tm3 = fmax3(sc[1][2], sc[1][3], sc[2][0]);
    float tm4 = fmax3(sc[2][1], sc[2][2], sc[2][3]);
    float tm5 = fmax3(sc[3][0], sc[3][1], sc[3][2]);
    tm = fmax3(tm, tm2, sc[3][3]);
    tm2 = fmax3(tm3, tm4, tm5);
    tm = fmaxf(tm, tm2);
    tm = fmaxf(tm, __shfl_xor(tm, 16));
    tm = fmaxf(tm, __shfl_xor(tm, 32));
    if (__any(tm > THR_DEFER)) {  // defer-max: rare after warmup
      const float pos = fmaxf(tm, 0.f);
      const float corr = exp2f(-pos);
      const f32x4 posv = {pos, pos, pos, pos};
      nmr4 -= posv;  // m += pos
      float cr[4];
      for (int r = 0; r < 4; ++r) cr[r] = __shfl(corr, lg * 4 + r);
      for (int r = 0; r < 4; ++r) lsum4[r] *= cr[r];
      for (int dt = 0; dt < 4; ++dt)
        for (int r = 0; r < 4; ++r) ao[dt][r] *= cr[r];
      for (int ct = 0; ct < 4; ++ct) sc[ct] -= posv;  // re-bias to new m
    }
#pragma unroll
    for (int ct = 0; ct < 4; ++ct) {
      const float p0 = exp2f(sc[ct][0]);
      const float p1 = exp2f(sc[ct][1]);
      const float p2 = exp2f(sc[ct][2]);
      const float p3 = exp2f(sc[ct][3]);
      f16x2 a = pk2(p0, p1);
      f16x2 bq = pk2(p2, p3);
      f16x4 ph = {a[0], a[1], bq[0], bq[1]};
      *(f16x4*)&pw[lr * 64 + ((ct * 16 + lg * 4) ^ pswz)] = ph;
    }
    // ---- PV + MFMA row-sum (matrix pipe does the reduction) ----
    f16x8 pf0 = *(const f16x8*)&pw[lr * 64 + ((lg * 8) ^ pswz)];
    f16x8 pf1 = *(const f16x8*)&pw[lr * 64 + ((32 + lg * 8) ^ pswz)];
    __builtin_amdgcn_s_setprio(1);
    lsum4 = MFMA16(pf0, ones8, lsum4);
    lsum4 = MFMA16(pf1, ones8, lsum4);
    for (int dt = 0; dt < 4; ++dt) {
      f16x8 vf0 = *(const f16x8*)&Vls[(dt * 16 + lr) * 64 + ((lg * 8) ^ pswz)];
      f16x8 vf1 = *(const f16x8*)&Vls[(dt * 16 + lr) * 64 + ((32 + lg * 8) ^ pswz)];
      ao[dt] = MFMA16(pf0, vf0, ao[dt]);
      ao[dt] = MFMA16(pf1, vf1, ao[dt]);
    }
    __builtin_amdgcn_s_setprio(0);
    __syncthreads();  // all waves done reading Kls/Vls
    if (t + 1 < NT) {  // write-late: staged regs -> LDS
      *(f16x8*)&Kls[lofs0] = kr0;
      *(f16x8*)&Kls[lofs1] = kr1;
      *(f16x8*)&Vls[lofs0] = vr0;
      *(f16x8*)&Vls[lofs1] = vr1;
      __syncthreads();
    }
  }
  // final: lsum4 already in C-layout (q = lg*4+r) -> no shuffles
  for (int r = 0; r < 4; ++r) {
    const float inv = 1.f / lsum4[r];
    const int row = q0 + w * 16 + lg * 4 + r;
    for (int dt = 0; dt < 4; ++dt) {
      const int col = h * 64 + dt * 16 + lr;
      AO[((size_t)b * 2048 + row) * 1024 + col] = (_Float16)(ao[dt][r] * inv);
    }
  }
}

extern "C" void kernel_launch(void* const* d_in, const int* in_sizes, int n_in,
                              void* d_out, int out_size, void* d_ws, size_t ws_size,
                              hipStream_t stream) {
  const float* x = (const float*)d_in[0];
  const float* wqkv = (const float*)d_in[2];
  const float* wout = (const float*)d_in[3];
  float* out = (float*)d_out;

  _Float16* xb = (_Float16*)d_ws;                  // 4096*1024
  _Float16* wqkvt = xb + (size_t)4096 * 1024;      // 3072*1024
  _Float16* woutt = wqkvt + (size_t)3072 * 1024;   // 1024*1024
  _Float16* q = woutt + (size_t)1024 * 1024;       // 32*2048*64
  _Float16* k = q + (size_t)4194304;
  _Float16* vt = k + (size_t)4194304;
  _Float16* aobuf = vt + (size_t)4194304;          // 4096*1024

  prep_kernel<<<8192, 256, 0, stream>>>(x, xb, wqkv, wqkvt, wout, woutt);
  gemm128<0, 4><<<768, 256, 0, stream>>>(xb, wqkvt, 1024, q, k, vt, nullptr, 3072);
  attn_kernel<<<1024, 256, 0, stream>>>(q, k, vt, aobuf);
  gemm128<1, 2><<<512, 256, 0, stream>>>(aobuf, woutt, 1024, nullptr, nullptr, nullptr,
                                         out, 1024);
}

// Round 14
// 140.635 us; speedup vs baseline: 1.0912x; 1.0912x over previous
//
#include <hip/hip_runtime.h>
#include <hip/hip_bf16.h>

typedef _Float16 f16x8 __attribute__((ext_vector_type(8)));
typedef _Float16 f16x4 __attribute__((ext_vector_type(4)));
typedef _Float16 f16x2 __attribute__((ext_vector_type(2)));
typedef __fp16 h16x2 __attribute__((ext_vector_type(2)));
typedef float f32x4 __attribute__((ext_vector_type(4)));
typedef unsigned int u32;

#define MFMA16(a, b, c) __builtin_amdgcn_mfma_f32_16x16x32_f16(a, b, c, 0, 0, 0)

// q pre-scale: sqrt(64) * log2(e)  (exp2-domain softmax)
#define QSCALE 11.54156032f
// defer-max threshold (log2 domain; ~8 nats). P bounded by 2^11.55 < f16 max.
#define THR_DEFER 11.54156032f

__device__ __forceinline__ void gld16(const void* g, void* l) {
  using gp_t = const __attribute__((address_space(1))) u32*;
  using lp_t = __attribute__((address_space(3))) u32*;
  __builtin_amdgcn_global_load_lds((gp_t)g, (lp_t)l, 16, 0, 0);
}

__device__ __forceinline__ float fmax3(float a, float b, float c) {
  float d;
  asm("v_max3_f32 %0, %1, %2, %3" : "=v"(d) : "v"(a), "v"(b), "v"(c));
  return d;
}

__device__ __forceinline__ f16x2 pk2(float lo, float hi) {
  h16x2 r = __builtin_amdgcn_cvt_pkrtz(lo, hi);
  return __builtin_bit_cast(f16x2, r);
}

__device__ __forceinline__ float sum2_acc(f16x2 v, float acc) {
#if __has_builtin(__builtin_amdgcn_fdot2)
  const h16x2 one2 = {(__fp16)1.0f, (__fp16)1.0f};
  return __builtin_amdgcn_fdot2(__builtin_bit_cast(h16x2, v), one2, acc, false);
#else
  return acc + (float)v[0] + (float)v[1];
#endif
}

// ---------------- fused prep: x f32->f16 + both weight transposes ----------
__global__ __launch_bounds__(256) void prep_kernel(
    const float* __restrict__ x, _Float16* __restrict__ xb,
    const float* __restrict__ wqkv, _Float16* __restrict__ wqkvt,
    const float* __restrict__ wout, _Float16* __restrict__ woutt) {
  __shared__ float t[32][33];
  const int bid = blockIdx.x, tid = threadIdx.x;
  if (bid < 4096) {
    const int i = (bid * 256 + tid) * 4;
    float4 v = *(const float4*)(x + i);
    f16x4 h = {(_Float16)v.x, (_Float16)v.y, (_Float16)v.z, (_Float16)v.w};
    *(f16x4*)(xb + i) = h;
    return;
  }
  const float* in;
  _Float16* out;
  int C, bx, by;
  if (bid < 7168) {
    const int b2 = bid - 4096;
    in = wqkv; out = wqkvt; C = 3072;
    bx = (b2 % 96) * 32; by = (b2 / 96) * 32;
  } else {
    const int b2 = bid - 7168;
    in = wout; out = woutt; C = 1024;
    bx = (b2 & 31) * 32; by = (b2 >> 5) * 32;
  }
  const int tx = tid & 31, ty = tid >> 5;
  for (int i = 0; i < 32; i += 8)
    t[ty + i][tx] = in[(size_t)(by + ty + i) * C + bx + tx];
  __syncthreads();
  for (int i = 0; i < 32; i += 8)
    out[(size_t)(bx + ty + i) * 1024 + by + tx] = (_Float16)t[tx][ty + i];
}

// ---------------- 128xBN tile GEMM, BK=64 (unchanged from R12) -------------
template <int MODE, int NTILE>
__global__ __launch_bounds__(256) void gemm128(
    const _Float16* __restrict__ A, const _Float16* __restrict__ Bt, int Kd,
    _Float16* __restrict__ qo, _Float16* __restrict__ ko, _Float16* __restrict__ vt,
    float* __restrict__ fo, int Nd) {
  constexpr int BN = NTILE * 32;
  constexpr int SHSZ = (MODE == 0) ? 16640 : (128 * 64 + BN * 64);
  __shared__ __align__(16) _Float16 SH[SHSZ];
  _Float16* As = SH;
  _Float16* Bs = SH + 128 * 64;
  const int tid = threadIdx.x;
  const int w = tid >> 6, l = tid & 63;
  const int wm = w >> 1, wn = w & 1;
  const int lr = l & 15, lg = l >> 4;
  const int nwg = gridDim.x;
  int lin = blockIdx.x;
  lin = (lin & 7) * (nwg >> 3) + (lin >> 3);
  const int m0 = (lin & 31) * 128, n0 = (lin >> 5) * BN;

  const int srow = tid >> 3;
  const int scol = ((tid & 7) ^ (srow & 7)) * 8;
  const int swzr = (lr & 7) << 3;

  f32x4 acc[4][NTILE];
  for (int i = 0; i < 4; ++i)
    for (int j = 0; j < NTILE; ++j) acc[i][j] = (f32x4){0.f, 0.f, 0.f, 0.f};

  const int NT = Kd >> 6;
  for (int kt = 0; kt < NT; ++kt) {
    const int k0 = kt * 64;
    for (int c = 0; c < 4; ++c) {
      const int row = c * 32 + srow;
      gld16(A + (size_t)(m0 + row) * Kd + k0 + scol, &As[(c * 32 + w * 8) * 64]);
    }
    for (int c = 0; c < NTILE; ++c) {
      const int row = c * 32 + srow;
      gld16(Bt + (size_t)(n0 + row) * Kd + k0 + scol, &Bs[(c * 32 + w * 8) * 64]);
    }
    __syncthreads();
    for (int kk = 0; kk < 2; ++kk) {
      f16x8 af[4], bf[NTILE];
      const int cofs = (kk * 32 + lg * 8) ^ swzr;
      for (int mt = 0; mt < 4; ++mt)
        af[mt] = *(const f16x8*)&As[(wm * 64 + mt * 16 + lr) * 64 + cofs];
      for (int nt = 0; nt < NTILE; ++nt)
        bf[nt] = *(const f16x8*)&Bs[(wn * (NTILE * 16) + nt * 16 + lr) * 64 + cofs];
      for (int mt = 0; mt < 4; ++mt)
        for (int nt = 0; nt < NTILE; ++nt)
          acc[mt][nt] = MFMA16(af[mt], bf[nt], acc[mt][nt]);
    }
    __syncthreads();
  }

  if (MODE == 0 && n0 >= 2048) {
    // V-section block: transpose via LDS, store V^T rows coalesced.
    for (int mt = 0; mt < 4; ++mt)
      for (int nt = 0; nt < NTILE; ++nt)
        for (int r = 0; r < 4; ++r) {
          const int row = wm * 64 + mt * 16 + lg * 4 + r;    // ns-rel
          const int col = wn * (NTILE * 16) + nt * 16 + lr;  // gn-rel
          SH[row * 130 + col] = (_Float16)acc[mt][nt][r];
        }
    __syncthreads();
    const int b = m0 >> 11;
    const int hbase = (n0 & 1023) >> 6;
    const int c = tid >> 1, half = tid & 1;
    const int h2 = c >> 6, d = c & 63;
    _Float16* dst = vt + ((size_t)((b * 16 + hbase + h2) * 64 + d)) * 2048 +
                    (m0 & 2047) + half * 64;
    for (int j = 0; j < 8; ++j) {
      f16x8 v;
      for (int e = 0; e < 8; ++e) v[e] = SH[(half * 64 + j * 8 + e) * 130 + c];
      *(f16x8*)(dst + j * 8) = v;
    }
    return;
  }

  for (int mt = 0; mt < 4; ++mt)
    for (int nt = 0; nt < NTILE; ++nt) {
      const int gmB = m0 + wm * 64 + mt * 16 + lg * 4;
      const int gn = n0 + wn * (NTILE * 16) + nt * 16 + lr;
      for (int r = 0; r < 4; ++r) {
        const int gm = gmB + r;
        const float v = acc[mt][nt][r];
        if (MODE == 0) {
          const int b = gm >> 11, ns = gm & 2047;
          const int sect = gn >> 10, rem = gn & 1023;
          const int h = rem >> 6, d = rem & 63;
          const size_t bh = (size_t)b * 16 + h;
          if (sect == 0)
            qo[(bh * 2048 + ns) * 64 + d] = (_Float16)(v * QSCALE);
          else
            ko[(bh * 2048 + ns) * 64 + d] = (_Float16)v;
        } else {
          fo[(size_t)gm * Nd + gn] = v;
        }
      }
    }
}

// ---------------- flash attention v11 ----------------
// v9's exact instruction stream + K/V double-buffered in LDS with ONE barrier
// per tile (write-late lands in the alternate buffer; barrier at tile end).
// Buffer safety: tile t reads buf[c], writes buf[c^1] after PV; t-1's reads
// of buf[c^1] are separated from these writes by the end-of-(t-1) barrier.
// LDS 40KB -> 4 blocks/CU = the existing grid limit (occupancy unchanged).
__global__ __launch_bounds__(256) void attn_kernel(
    const _Float16* __restrict__ Q, const _Float16* __restrict__ K,
    const _Float16* __restrict__ Vt, _Float16* __restrict__ AO) {
  __shared__ __align__(16) _Float16 Kls[2][64 * 64];   // dbuf [key][d], swizzled
  __shared__ __align__(16) _Float16 Vls[2][64 * 64];   // dbuf [d][key], swizzled
  __shared__ __align__(16) _Float16 Pls[4 * 16 * 64];  // per-wave [q][key], swizzled
  const int bid = blockIdx.x;
  const int xcd = bid & 7, slot = bid >> 3;  // HW: consecutive bid -> XCDs RR
  const int bh = xcd * 4 + (slot >> 5);      // 4 bh per XCD (KV fits per-XCD L2)
  const int qt = slot & 31;
  const int b = bh >> 4, h = bh & 15;
  const int tid = threadIdx.x, w = tid >> 6, l = tid & 63;
  const int lr = l & 15, lg = l >> 4;
  const int q0 = qt * 64;
  const int pswz = (lr & 7) << 3;

  f16x8 qf[2];
  {
    const _Float16* qp = Q + ((size_t)bh * 2048 + q0 + w * 16 + lr) * 64 + lg * 8;
    qf[0] = *(const f16x8*)qp;
    qf[1] = *(const f16x8*)(qp + 32);
  }
  float mrun = -INFINITY, lsum = 0.f;  // state for q = w*16 + lr
  f32x4 ao[4];
  for (int dt = 0; dt < 4; ++dt) ao[dt] = (f32x4){0.f, 0.f, 0.f, 0.f};

  const int srow = tid >> 2, cb = tid & 3;
  const _Float16* Kbase = K + ((size_t)bh * 2048 + srow) * 64 + cb * 8;
  const _Float16* Vbase = Vt + ((size_t)bh * 64 + srow) * 2048 + cb * 8;
  const int lofs0 = srow * 64 + ((cb ^ (srow & 7)) << 3);
  const int lofs1 = srow * 64 + (((cb + 4) ^ (srow & 7)) << 3);

  f16x8 kr0, kr1, vr0, vr1;
  kr0 = *(const f16x8*)(Kbase);
  kr1 = *(const f16x8*)(Kbase + 32);
  vr0 = *(const f16x8*)(Vbase);
  vr1 = *(const f16x8*)(Vbase + 32);
  *(f16x8*)&Kls[0][lofs0] = kr0;
  *(f16x8*)&Kls[0][lofs1] = kr1;
  *(f16x8*)&Vls[0][lofs0] = vr0;
  *(f16x8*)&Vls[0][lofs1] = vr1;
  __syncthreads();

  _Float16* pw = &Pls[w * (16 * 64)];
  const int NT = 2048 / 64;
  int c = 0;
  for (int t = 0; t < NT; ++t) {
    if (t + 1 < NT) {  // issue next tile's loads early
      const size_t g = (size_t)(t + 1) * 64;
      kr0 = *(const f16x8*)(Kbase + g * 64);
      kr1 = *(const f16x8*)(Kbase + g * 64 + 32);
      vr0 = *(const f16x8*)(Vbase + g);
      vr1 = *(const f16x8*)(Vbase + g + 32);
    }
    const _Float16* Kc = Kls[c];
    const _Float16* Vc = Vls[c];
    // ---- S^T = K Q : sc[ct][r] = S[key=16ct+4lg+r][q=w*16+lr] ----
    f32x4 sc[4];
    for (int ct = 0; ct < 4; ++ct) sc[ct] = (f32x4){0.f, 0.f, 0.f, 0.f};
    __builtin_amdgcn_s_setprio(1);
    for (int ct = 0; ct < 4; ++ct)
      for (int kg = 0; kg < 2; ++kg) {
        f16x8 kf =
            *(const f16x8*)&Kc[(ct * 16 + lr) * 64 + ((kg * 32 + lg * 8) ^ pswz)];
        sc[ct] = MFMA16(kf, qf[kg], sc[ct]);
      }
    __builtin_amdgcn_s_setprio(0);
    // ---- softmax over this lane's 16 keys (v_max3 tree) ----
    float tm = fmax3(sc[0][0], sc[0][1], sc[0][2]);
    float tm2 = fmax3(sc[0][3], sc[1][0], sc[1][1]);
    float tm3 = fmax3(sc[1][2], sc[1][3], sc[2][0]);
    float tm4 = fmax3(sc[2][1], sc[2][2], sc[2][3]);
    float tm5 = fmax3(sc[3][0], sc[3][1], sc[3][2]);
    tm = fmax3(tm, tm2, sc[3][3]);
    tm2 = fmax3(tm3, tm4, tm5);
    tm = fmaxf(tm, tm2);
    tm = fmaxf(tm, __shfl_xor(tm, 16));
    tm = fmaxf(tm, __shfl_xor(tm, 32));
    if (__any(tm > mrun + THR_DEFER)) {  // defer-max (T13): rescale rarely
      const float nm = fmaxf(mrun, tm);
      const float corr = exp2f(mrun - nm);
      mrun = nm;
      lsum *= corr;
      float cr[4];
      for (int r = 0; r < 4; ++r) cr[r] = __shfl(corr, lg * 4 + r);
      for (int dt = 0; dt < 4; ++dt)
        for (int r = 0; r < 4; ++r) ao[dt][r] *= cr[r];
    }
#pragma unroll
    for (int ct = 0; ct < 4; ++ct) {
      const float p0 = exp2f(sc[ct][0] - mrun);
      const float p1 = exp2f(sc[ct][1] - mrun);
      const float p2 = exp2f(sc[ct][2] - mrun);
      const float p3 = exp2f(sc[ct][3] - mrun);
      f16x2 a = pk2(p0, p1);
      f16x2 bq = pk2(p2, p3);
      f16x4 ph = {a[0], a[1], bq[0], bq[1]};
      *(f16x4*)&pw[lr * 64 + ((ct * 16 + lg * 4) ^ pswz)] = ph;
      lsum = sum2_acc(a, lsum);
      lsum = sum2_acc(bq, lsum);
    }
    // ---- PV ----
    f16x8 pf0 = *(const f16x8*)&pw[lr * 64 + ((lg * 8) ^ pswz)];
    f16x8 pf1 = *(const f16x8*)&pw[lr * 64 + ((32 + lg * 8) ^ pswz)];
    __builtin_amdgcn_s_setprio(1);
    for (int dt = 0; dt < 4; ++dt) {
      f16x8 vf0 = *(const f16x8*)&Vc[(dt * 16 + lr) * 64 + ((lg * 8) ^ pswz)];
      f16x8 vf1 = *(const f16x8*)&Vc[(dt * 16 + lr) * 64 + ((32 + lg * 8) ^ pswz)];
      ao[dt] = MFMA16(pf0, vf0, ao[dt]);
      ao[dt] = MFMA16(pf1, vf1, ao[dt]);
    }
    __builtin_amdgcn_s_setprio(0);
    if (t + 1 < NT) {  // write-late into the ALTERNATE buffer, then one barrier
      *(f16x8*)&Kls[c ^ 1][lofs0] = kr0;
      *(f16x8*)&Kls[c ^ 1][lofs1] = kr1;
      *(f16x8*)&Vls[c ^ 1][lofs0] = vr0;
      *(f16x8*)&Vls[c ^ 1][lofs1] = vr1;
      __syncthreads();
    }
    c ^= 1;
  }
  // final: total sum for q=w*16+lr, then shuffle inverse to ao rows (lg*4+r)
  lsum += __shfl_xor(lsum, 16);
  lsum += __shfl_xor(lsum, 32);
  const float inv = 1.f / lsum;
  float invr[4];
  for (int r = 0; r < 4; ++r) invr[r] = __shfl(inv, lg * 4 + r);
  for (int r = 0; r < 4; ++r) {
    const int row = q0 + w * 16 + lg * 4 + r;
    for (int dt = 0; dt < 4; ++dt) {
      const int col = h * 64 + dt * 16 + lr;
      AO[((size_t)b * 2048 + row) * 1024 + col] = (_Float16)(ao[dt][r] * invr[r]);
    }
  }
}

extern "C" void kernel_launch(void* const* d_in, const int* in_sizes, int n_in,
                              void* d_out, int out_size, void* d_ws, size_t ws_size,
                              hipStream_t stream) {
  const float* x = (const float*)d_in[0];
  const float* wqkv = (const float*)d_in[2];
  const float* wout = (const float*)d_in[3];
  float* out = (float*)d_out;

  _Float16* xb = (_Float16*)d_ws;                  // 4096*1024
  _Float16* wqkvt = xb + (size_t)4096 * 1024;      // 3072*1024
  _Float16* woutt = wqkvt + (size_t)3072 * 1024;   // 1024*1024
  _Float16* q = woutt + (size_t)1024 * 1024;       // 32*2048*64
  _Float16* k = q + (size_t)4194304;
  _Float16* vt = k + (size_t)4194304;
  _Float16* aobuf = vt + (size_t)4194304;          // 4096*1024

  prep_kernel<<<8192, 256, 0, stream>>>(x, xb, wqkv, wqkvt, wout, woutt);
  gemm128<0, 4><<<768, 256, 0, stream>>>(xb, wqkvt, 1024, q, k, vt, nullptr, 3072);
  attn_kernel<<<1024, 256, 0, stream>>>(q, k, vt, aobuf);
  gemm128<1, 2><<<512, 256, 0, stream>>>(aobuf, woutt, 1024, nullptr, nullptr, nullptr,
                                         out, 1024);
}